// Round 14
// baseline (261.160 us; speedup 1.0000x reference)
//
#include <hip/hip_runtime.h>
#include <math.h>

#define D 128
#define SB 256
#define NBMAX 256
#define BSTRIDE 209   // LDS row stride for bin table: 209 mod 32 = 17, coprime w/ 32 banks

typedef __attribute__((ext_vector_type(8))) short bf16x8;
typedef __attribute__((ext_vector_type(4))) float f32x4;

// round-to-nearest-even f32 -> bf16 bits
__device__ inline unsigned f2bf(float f) {
    unsigned u = __float_as_uint(f);
    return (u + 0x7FFFu + ((u >> 16) & 1u)) >> 16;
}

// ---------------------------------------------------------------------------
// prep: one kernel for all precompute + histogram. 256 threads/block,
// heavy sections split-k across two halves (j = t&127, half = t>>7).
//   blocks [0,384)   : folded weights -> bf16 B-fragment-packed Wpk
//   blocks [384,387) : biases bqa/bka/bva (f32)
//   block  387       : global bounds[] (for k_scatter)
//   blocks [388,517) : interval tables AB/MB (recompute bounds locally)
//   blocks [517,645) : Wm2 -> bf16 B-fragment-packed Wpk2
//   blocks 645+      : degree histogram (deg pre-zeroed by memsetAsync)
// ---------------------------------------------------------------------------
__global__ __launch_bounds__(256) void prep(
    const float* __restrict__ Wq, const float* __restrict__ bq,
    const float* __restrict__ Wk, const float* __restrict__ bk,
    const float* __restrict__ Wv, const float* __restrict__ bv,
    const float* __restrict__ Wa1, const float* __restrict__ ba1,
    const float* __restrict__ Wm1, const float* __restrict__ bm1,
    const float* __restrict__ We1, const float* __restrict__ be1,
    const float* __restrict__ We2, const float* __restrict__ be2,
    const float* __restrict__ Wm2,
    const int* __restrict__ ei, int E,
    ushort* __restrict__ Wpk, ushort* __restrict__ Wpk2,
    float* __restrict__ bqa, float* __restrict__ bka, float* __restrict__ bva,
    float* __restrict__ bounds,
    float2* __restrict__ AB, float2* __restrict__ MB,
    int* __restrict__ deg)
{
    __shared__ float smem[1536];
    int b = blockIdx.x;
    int t = threadIdx.x;
    int j = t & 127, half = t >> 7;
    if (b < 384) {
        int which = b >> 7, i = b & 127;   // i = k index
        const float *A, *B;
        if (which == 0)      { A = Wq; B = Wa1; }
        else if (which == 1) { A = Wk; B = Wa1 + 128 * D; }
        else                 { A = Wv; B = Wm1; }
        float acc = 0.f;
        for (int k = half * 64; k < half * 64 + 64; k++) acc += A[i * D + k] * B[k * D + j];
        smem[t] = acc;
        __syncthreads();
        if (half == 0) {
            float v = smem[j] + smem[128 + j];
            int gc = which * 128 + j;
            int nt = gc >> 4;
            int ks = i >> 5;
            int lane = (((i >> 3) & 3) << 4) | (gc & 15);
            int j8 = i & 7;
            Wpk[((nt * 4 + ks) * 64 + lane) * 8 + j8] = (ushort)f2bf(v);
        }
    } else if (b < 387) {
        int which = b - 384;
        const float *bias, *B, *extra; float *out;
        if (which == 0)      { bias = bq; B = Wa1;           out = bqa; extra = ba1; }
        else if (which == 1) { bias = bk; B = Wa1 + 128 * D; out = bka; extra = nullptr; }
        else                 { bias = bv; B = Wm1;           out = bva; extra = bm1; }
        float acc = 0.f;
        for (int k = half * 64; k < half * 64 + 64; k++) acc += bias[k] * B[k * D + j];
        smem[t] = acc;
        __syncthreads();
        if (half == 0) out[j] = smem[j] + smem[128 + j] + (extra ? extra[j] : 0.f);
    } else if (b == 387) {
        float* sb = smem;
        if (t < 128) {
            float w = We1[t], bb = be1[t];
            float th = (w != 0.f) ? (-bb / w) : 2.f;
            sb[t] = fminf(fmaxf(th, 0.f), 1.f);
        }
        __syncthreads();
        for (int k = 2; k <= 128; k <<= 1)
            for (int jj = k >> 1; jj > 0; jj >>= 1) {
                if (t < 128) {
                    int ixj = t ^ jj;
                    if (ixj > t) {
                        float a = sb[t], c = sb[ixj];
                        bool up = ((t & k) == 0);
                        if (up ? (a > c) : (a < c)) { sb[t] = c; sb[ixj] = a; }
                    }
                }
                __syncthreads();
            }
        if (t == 0) { bounds[0] = 0.f; bounds[129] = 1.f; }
        if (t < 128) bounds[1 + t] = sb[t];
    } else if (b < 517) {
        float* sb = smem;            // 128
        float* Ae = smem + 128;      // 128
        float* Be = smem + 256;      // 128
        float* P  = smem + 384;      // 1024
        if (t < 128) {
            float w = We1[t], bb = be1[t];
            float th = (w != 0.f) ? (-bb / w) : 2.f;
            sb[t] = fminf(fmaxf(th, 0.f), 1.f);
        }
        __syncthreads();
        for (int k = 2; k <= 128; k <<= 1)
            for (int jj = k >> 1; jj > 0; jj >>= 1) {
                if (t < 128) {
                    int ixj = t ^ jj;
                    if (ixj > t) {
                        float a = sb[t], c = sb[ixj];
                        bool up = ((t & k) == 0);
                        if (up ? (a > c) : (a < c)) { sb[t] = c; sb[ixj] = a; }
                    }
                }
                __syncthreads();
            }
        int i = b - 388;                  // interval 0..128
        float lo = (i == 0)   ? 0.f : sb[i - 1];
        float hi = (i == 128) ? 1.f : sb[i];
        float m = 0.5f * (lo + hi);
        float ae = 0.f, be = 0.f;
        for (int k = half * 64; k < half * 64 + 64; k++) {
            float ww = We1[k], bb2 = be1[k];
            if (m * ww + bb2 > 0.f) { ae += ww * We2[k * D + j]; be += bb2 * We2[k * D + j]; }
        }
        P[t] = ae; P[256 + t] = be;
        __syncthreads();
        if (half == 0) {
            Ae[j] = P[j] + P[128 + j];
            Be[j] = P[256 + j] + P[384 + j] + be2[j];
        }
        __syncthreads();
        float aa = 0.f, ba = 0.f, am = 0.f, bm = 0.f;
        for (int l2 = half * 64; l2 < half * 64 + 64; l2++) {
            float ael = Ae[l2], bel = Be[l2];
            float wa = Wa1[(256 + l2) * D + j];
            float wm = Wm1[(128 + l2) * D + j];
            aa += ael * wa; ba += bel * wa;
            am += ael * wm; bm += bel * wm;
        }
        P[t] = aa; P[256 + t] = ba; P[512 + t] = am; P[768 + t] = bm;
        __syncthreads();
        if (half == 0) {
            AB[i * 128 + j] = make_float2(P[j] + P[128 + j], P[256 + j] + P[384 + j]);
            MB[i * 128 + j] = make_float2(P[512 + j] + P[640 + j], P[768 + j] + P[896 + j]);
        }
    } else if (b < 645) {
        if (t < 128) {
            int i = b - 517;                  // k row of Wm2
            int nt = t >> 4;
            int ks = i >> 5;
            int lane = (((i >> 3) & 3) << 4) | (t & 15);
            int j8 = i & 7;
            Wpk2[((nt * 4 + ks) * 64 + lane) * 8 + j8] = (ushort)f2bf(Wm2[i * D + t]);
        }
    } else {
        int e = (b - 645) * 256 + t;
        if (e < E) atomicAdd(deg + ei[E + e], 1);
    }
}

// ---------------------------------------------------------------------------
// CSR scan + contention-free counting sort for degree-balanced node pairing.
// k_scan1: block sums of deg + per-block 64-bin LDS histogram -> blockBin.
// k_scan23: exclusive CSR offsets + nodePerm. Bin prefix-scan done PER BLOCK
//           redundantly in LDS (stride BSTRIDE, conflict-free; reads are
//           address-independent so they pipeline) — no binscan kernel.
// k_binscan_fallback: only if NB > BSTRIDE (not hit at N=50000).
// off[] = exclusive starts; k_scatter bumps off[col] -> inclusive ends.
// ---------------------------------------------------------------------------
__global__ __launch_bounds__(SB) void k_scan1(const int* __restrict__ deg, int N,
                                              int* __restrict__ partial,
                                              int* __restrict__ blockBin)
{
    __shared__ int ls[SB];
    __shared__ int lbin[64];
    int t = threadIdx.x;
    if (t < 64) lbin[t] = 0;
    int i = blockIdx.x * SB + t;
    int v = (i < N) ? deg[i] : 0;
    ls[t] = v;
    __syncthreads();
    if (i < N) atomicAdd(&lbin[v < 63 ? v : 63], 1);
    for (int s = SB / 2; s > 0; s >>= 1) {
        if (t < s) ls[t] += ls[t + s];
        __syncthreads();
    }
    if (t == 0) partial[blockIdx.x] = ls[0];
    if (t < 64) blockBin[t * NBMAX + blockIdx.x] = lbin[t];
}

__global__ __launch_bounds__(256) void k_binscan_fallback(int* __restrict__ blockBin, int NB,
                                                          int* __restrict__ binStartG)
{
    // serial global fallback (NB > BSTRIDE only); layout matches k_scan23's
    // fused path being bypassed: writes exclusive prefixes in place + binStartG
    __shared__ int tot[64];
    int t = threadIdx.x;
    if (t < 64) {
        int run = 0;
        for (int blk = 0; blk < NB; blk++) {
            int v = blockBin[t * NBMAX + blk];
            blockBin[t * NBMAX + blk] = run;
            run += v;
        }
        tot[t] = run;
    }
    __syncthreads();
    if (t == 0) {
        int acc = 0;
        for (int x = 0; x < 64; x++) { binStartG[x] = acc; acc += tot[x]; }
    }
}

template<int FUSED>
__global__ __launch_bounds__(SB) void k_scan23(const int* __restrict__ deg, int N,
                                               const int* __restrict__ partial, int NB,
                                               const int* __restrict__ blockBin,
                                               const int* __restrict__ binStartG,
                                               int* __restrict__ nodePerm,
                                               int* __restrict__ off)
{
    __shared__ int lp[SB];
    __shared__ int ls[SB];
    __shared__ int lbin[64];
    __shared__ int bstart[65];
    __shared__ int buf[FUSED ? 64 * BSTRIDE : 1];
    int t = threadIdx.x;
    if (t < 64) lbin[t] = 0;

    if (FUSED) {
        // stage blockBin (layout [64][NBMAX]) into LDS, stride BSTRIDE
        for (int bin = 0; bin < 64; bin++)
            for (int col = t; col < NB; col += SB)
                buf[bin * BSTRIDE + col] = blockBin[bin * NBMAX + col];
        __syncthreads();
        // per-bin exclusive scan (64 lanes, one ds_read per iter, pipelined)
        if (t < 64) {
            int run = 0;
            for (int blk = 0; blk < NB; blk++) {
                int idx = t * BSTRIDE + blk;
                int v = buf[idx];
                buf[idx] = run;
                run += v;
            }
            bstart[t + 1] = run;
        }
        __syncthreads();
        if (t == 0) {
            int acc = 0;
            bstart[0] = 0;
            for (int x = 1; x <= 64; x++) { acc += bstart[x]; bstart[x] = acc; }
        }
        __syncthreads();
    } else {
        if (t < 64) bstart[t] = binStartG[t];
        __syncthreads();
    }

    int pv = (t < NB) ? partial[t] : 0;
    lp[t] = pv;
    __syncthreads();
    int pval = pv;
    for (int s = 1; s < SB; s <<= 1) {
        int add = (t >= s) ? lp[t - s] : 0;
        __syncthreads();
        pval += add;
        lp[t] = pval;
        __syncthreads();
    }
    int base = (blockIdx.x > 0) ? lp[blockIdx.x - 1] : 0;

    int i = blockIdx.x * SB + t;
    int v = (i < N) ? deg[i] : 0;
    ls[t] = v;
    __syncthreads();
    int val = v;
    for (int s = 1; s < SB; s <<= 1) {
        int add = (t >= s) ? ls[t - s] : 0;
        __syncthreads();
        val += add;
        ls[t] = val;
        __syncthreads();
    }
    if (i < N) {
        off[i] = base + val - v;
        int bidx = (v < 63 ? v : 63);
        int lr = atomicAdd(&lbin[bidx], 1);   // LDS arrival rank (block-local)
        int blockPfx = FUSED ? buf[bidx * BSTRIDE + blockIdx.x]
                             : blockBin[bidx * NBMAX + blockIdx.x];
        int pos = (FUSED ? bstart[bidx] : bstart[bidx]) + blockPfx + lr;
        nodePerm[pos] = i;
    }
}

// ---------------------------------------------------------------------------
// k_scatter: standalone (low VGPR, high occupancy). Packs records
// {row | interval<<17, bits(a)} into CSR slots, bumping off[col].
// ---------------------------------------------------------------------------
__global__ __launch_bounds__(256) void k_scatter(const int* __restrict__ ei,
                                                 const float* __restrict__ eattr, int E,
                                                 const float* __restrict__ bounds,
                                                 int* __restrict__ off, int2* __restrict__ recs)
{
    __shared__ float bnd[130];
    int t = threadIdx.x;
    if (t < 130) bnd[t] = bounds[t];
    __syncthreads();
    int e = blockIdx.x * 256 + t;
    if (e >= E) return;
    int row = ei[e], col = ei[E + e];
    float a = eattr[e];
    int lo = 0, hi = 128;
    while (lo < hi) { int mid = (lo + hi + 1) >> 1; if (bnd[mid] <= a) lo = mid; else hi = mid - 1; }
    int p = atomicAdd(off + col, 1);
    recs[p] = make_int2(row | (lo << 17), __float_as_int(a));
}

// ---------------------------------------------------------------------------
// node_gemm (MFMA): [N x 128] @ [128 x 384] in bf16, f32 accum.
// Epilogue writes qa as bf16 (ushort per channel) and packed bf16 kv.
// ---------------------------------------------------------------------------
__global__ __launch_bounds__(256) void node_gemm(
    const float* __restrict__ h, int N,
    const ushort* __restrict__ Wpk,
    const float* __restrict__ bqa, const float* __restrict__ bka, const float* __restrict__ bva,
    ushort* __restrict__ qb, unsigned* __restrict__ kv)
{
    __shared__ __align__(16) ushort hsb[64 * 128];
    int t = threadIdx.x;
    int row0 = blockIdx.x * 64;
#pragma unroll
    for (int i = 0; i < 4; i++) {
        int g = t + i * 256;
        int r = g >> 4, c = g & 15;
        int grow = row0 + r;
        float4 f0, f1;
        if (grow < N) {
            const float4* hp = (const float4*)(h + (size_t)grow * D + c * 8);
            f0 = hp[0]; f1 = hp[1];
        } else {
            f0 = make_float4(0.f, 0.f, 0.f, 0.f); f1 = f0;
        }
        ushort u[8] = { (ushort)f2bf(f0.x), (ushort)f2bf(f0.y), (ushort)f2bf(f0.z), (ushort)f2bf(f0.w),
                        (ushort)f2bf(f1.x), (ushort)f2bf(f1.y), (ushort)f2bf(f1.z), (ushort)f2bf(f1.w) };
        int pc = c ^ (r & 15);
        *(uint4*)&hsb[r * 128 + pc * 8] = *(uint4*)u;
    }
    __syncthreads();

    int w = t >> 6, l = t & 63;
    int lrow = w * 16 + (l & 15);
    f32x4 acc[24];
#pragma unroll
    for (int i = 0; i < 24; i++) acc[i] = (f32x4){0.f, 0.f, 0.f, 0.f};

    const bf16x8* WB = (const bf16x8*)Wpk;
#pragma unroll
    for (int ks = 0; ks < 4; ks++) {
        int c = (ks * 4 + (l >> 4)) ^ (l & 15);
        bf16x8 afrag = *(const bf16x8*)&hsb[lrow * 128 + c * 8];
#pragma unroll
        for (int nt = 0; nt < 24; nt++) {
            bf16x8 bfrag = WB[(nt * 4 + ks) * 64 + l];
            acc[nt] = __builtin_amdgcn_mfma_f32_16x16x32_bf16(afrag, bfrag, acc[nt], 0, 0, 0);
        }
    }

    int rbase = row0 + w * 16 + ((l >> 4) << 2);
    int cl = l & 15;
#pragma unroll
    for (int cc = 0; cc < 8; cc++) {
        float bqv = bqa[cc * 16 + cl];
        float bkv = bka[cc * 16 + cl];
        float bvv = bva[cc * 16 + cl];
        f32x4 aq = acc[cc], ak = acc[8 + cc], av = acc[16 + cc];
#pragma unroll
        for (int r = 0; r < 4; r++) {
            int row = rbase + r;
            if (row < N) {
                qb[(size_t)row * D + cc * 16 + cl] = (ushort)f2bf(aq[r] + bqv);
                kv[(size_t)row * D + cc * 16 + cl] =
                    (f2bf(av[r] + bvv) << 16) | f2bf(ak[r] + bkv);
            }
        }
    }
}

// ---------------------------------------------------------------------------
// node_all (R8 structure + degree-sorted pairing): 32 lanes per destination
// node (2 nodes/wave, paired via nodePerm so both have near-equal degree).
// Defer-max online softmax (rescale only when max grows by >8; ba2 dropped).
// 2-edge unroll batches 12 loads per pair. bf16 q input. Emits bf16 S + segsum.
// ---------------------------------------------------------------------------
__global__ __launch_bounds__(256) void node_all(
    const int2* __restrict__ recs, int N,
    const int* __restrict__ off, const int* __restrict__ nodePerm,
    const ushort* __restrict__ qb, const unsigned* __restrict__ kv,
    const float2* __restrict__ AB, const float2* __restrict__ MB,
    const float* __restrict__ Wa2,
    unsigned* __restrict__ Sb, float* __restrict__ segsum)
{
    int t = threadIdx.x;
    int l = t & 31;
    int n0 = blockIdx.x * 8 + (t >> 5);
    bool valid = (n0 < N);
    int n = valid ? nodePerm[n0] : 0;
    int start = 0, end = 0;
    if (valid) {
        end = off[n];
        start = (n > 0) ? off[n - 1] : 0;
    }

    const char* kvc = (const char*)kv;
    const char* ABc = (const char*)AB;
    const char* MBc = (const char*)MB;

    uint2 qp = valid ? *(const uint2*)(qb + (size_t)n * D + 4 * l) : make_uint2(0u, 0u);
    float q0 = __uint_as_float(qp.x << 16);
    float q1 = __uint_as_float(qp.x & 0xFFFF0000u);
    float q2 = __uint_as_float(qp.y << 16);
    float q3 = __uint_as_float(qp.y & 0xFFFF0000u);
    float4 w4 = *(const float4*)(Wa2 + 4 * l);

    float m_run = -INFINITY;
    float a0 = 0.f, a1 = 0.f, a2 = 0.f, a3 = 0.f, ssum = 0.f;

    int idx = start;
    for (; idx + 2 <= end; idx += 2) {
        int2 rec1 = recs[idx];
        int2 rec2 = recs[idx + 1];
        unsigned u1 = (unsigned)rec1.x, u2 = (unsigned)rec2.x;
        float at1 = __int_as_float(rec1.y), at2 = __int_as_float(rec2.y);
        int rb1 = (int)(u1 & 0x1FFFFu) << 9, tb1 = (int)(u1 >> 17) << 10;
        int rb2 = (int)(u2 & 0x1FFFFu) << 9, tb2 = (int)(u2 >> 17) << 10;

        uint4 kp1 = *(const uint4*)(kvc + rb1 + (l << 4));
        uint4 kp2 = *(const uint4*)(kvc + rb2 + (l << 4));
        float4 ab0a = *(const float4*)(ABc + tb1 + (l << 5));
        float4 ab1a = *(const float4*)(ABc + tb1 + (l << 5) + 16);
        float4 mb0a = *(const float4*)(MBc + tb1 + (l << 5));
        float4 mb1a = *(const float4*)(MBc + tb1 + (l << 5) + 16);
        float4 ab0b = *(const float4*)(ABc + tb2 + (l << 5));
        float4 ab1b = *(const float4*)(ABc + tb2 + (l << 5) + 16);
        float4 mb0b = *(const float4*)(MBc + tb2 + (l << 5));
        float4 mb1b = *(const float4*)(MBc + tb2 + (l << 5) + 16);

        float p1 = fmaxf(q0 + __uint_as_float(kp1.x << 16) + at1 * ab0a.x + ab0a.y, 0.f) * w4.x
                 + fmaxf(q1 + __uint_as_float(kp1.y << 16) + at1 * ab0a.z + ab0a.w, 0.f) * w4.y
                 + fmaxf(q2 + __uint_as_float(kp1.z << 16) + at1 * ab1a.x + ab1a.y, 0.f) * w4.z
                 + fmaxf(q3 + __uint_as_float(kp1.w << 16) + at1 * ab1a.z + ab1a.w, 0.f) * w4.w;
        float p2 = fmaxf(q0 + __uint_as_float(kp2.x << 16) + at2 * ab0b.x + ab0b.y, 0.f) * w4.x
                 + fmaxf(q1 + __uint_as_float(kp2.y << 16) + at2 * ab0b.z + ab0b.w, 0.f) * w4.y
                 + fmaxf(q2 + __uint_as_float(kp2.z << 16) + at2 * ab1b.x + ab1b.y, 0.f) * w4.z
                 + fmaxf(q3 + __uint_as_float(kp2.w << 16) + at2 * ab1b.z + ab1b.w, 0.f) * w4.w;
#pragma unroll
        for (int s = 1; s < 32; s <<= 1) {
            p1 += __shfl_xor(p1, s, 64);
            p2 += __shfl_xor(p2, s, 64);
        }
        float d1 = p1 - m_run, d2 = p2 - m_run;
        if (fmaxf(d1, d2) > 8.f) {           // rare: max grew a lot (or first pair)
            float mN = fmaxf(fmaxf(p1, p2), m_run);
            float sc = __expf(m_run - mN);   // 0 on first pair
            a0 *= sc; a1 *= sc; a2 *= sc; a3 *= sc; ssum *= sc;
            m_run = mN; d1 = p1 - mN; d2 = p2 - mN;
        }
        float ex1 = __expf(d1), ex2 = __expf(d2);

        float x0 = __uint_as_float(kp1.x & 0xFFFF0000u) + at1 * mb0a.x + mb0a.y;
        float x1 = __uint_as_float(kp1.y & 0xFFFF0000u) + at1 * mb0a.z + mb0a.w;
        float x2 = __uint_as_float(kp1.z & 0xFFFF0000u) + at1 * mb1a.x + mb1a.y;
        float x3 = __uint_as_float(kp1.w & 0xFFFF0000u) + at1 * mb1a.z + mb1a.w;
        float y0 = __uint_as_float(kp2.x & 0xFFFF0000u) + at2 * mb0b.x + mb0b.y;
        float y1 = __uint_as_float(kp2.y & 0xFFFF0000u) + at2 * mb0b.z + mb0b.w;
        float y2 = __uint_as_float(kp2.z & 0xFFFF0000u) + at2 * mb1b.x + mb1b.y;
        float y3 = __uint_as_float(kp2.w & 0xFFFF0000u) + at2 * mb1b.z + mb1b.w;
        float s10 = x0 * __builtin_amdgcn_rcpf(1.f + __expf(-x0));
        float s11 = x1 * __builtin_amdgcn_rcpf(1.f + __expf(-x1));
        float s12 = x2 * __builtin_amdgcn_rcpf(1.f + __expf(-x2));
        float s13 = x3 * __builtin_amdgcn_rcpf(1.f + __expf(-x3));
        float s20 = y0 * __builtin_amdgcn_rcpf(1.f + __expf(-y0));
        float s21 = y1 * __builtin_amdgcn_rcpf(1.f + __expf(-y1));
        float s22 = y2 * __builtin_amdgcn_rcpf(1.f + __expf(-y2));
        float s23 = y3 * __builtin_amdgcn_rcpf(1.f + __expf(-y3));

        a0 = fmaf(ex2, s20, fmaf(ex1, s10, a0));
        a1 = fmaf(ex2, s21, fmaf(ex1, s11, a1));
        a2 = fmaf(ex2, s22, fmaf(ex1, s12, a2));
        a3 = fmaf(ex2, s23, fmaf(ex1, s13, a3));
        ssum += ex1 + ex2;
    }
    if (idx < end) {   // odd tail
        int2 rec = recs[idx];
        unsigned u1 = (unsigned)rec.x;
        float a = __int_as_float(rec.y);
        int rb = (int)(u1 & 0x1FFFFu) << 9, tb = (int)(u1 >> 17) << 10;
        uint4 kp = *(const uint4*)(kvc + rb + (l << 4));
        float4 ab0 = *(const float4*)(ABc + tb + (l << 5));
        float4 ab1 = *(const float4*)(ABc + tb + (l << 5) + 16);
        float4 mb0 = *(const float4*)(MBc + tb + (l << 5));
        float4 mb1 = *(const float4*)(MBc + tb + (l << 5) + 16);
        float p1 = fmaxf(q0 + __uint_as_float(kp.x << 16) + a * ab0.x + ab0.y, 0.f) * w4.x
                 + fmaxf(q1 + __uint_as_float(kp.y << 16) + a * ab0.z + ab0.w, 0.f) * w4.y
                 + fmaxf(q2 + __uint_as_float(kp.z << 16) + a * ab1.x + ab1.y, 0.f) * w4.z
                 + fmaxf(q3 + __uint_as_float(kp.w << 16) + a * ab1.z + ab1.w, 0.f) * w4.w;
#pragma unroll
        for (int s = 1; s < 32; s <<= 1) p1 += __shfl_xor(p1, s, 64);
        float d1 = p1 - m_run;
        if (d1 > 8.f) {
            float mN = p1;
            float sc = __expf(m_run - mN);
            a0 *= sc; a1 *= sc; a2 *= sc; a3 *= sc; ssum *= sc;
            m_run = mN; d1 = 0.f;
        }
        float ex = __expf(d1);
        float x0 = __uint_as_float(kp.x & 0xFFFF0000u) + a * mb0.x + mb0.y;
        float x1 = __uint_as_float(kp.y & 0xFFFF0000u) + a * mb0.z + mb0.w;
        float x2 = __uint_as_float(kp.z & 0xFFFF0000u) + a * mb1.x + mb1.y;
        float x3 = __uint_as_float(kp.w & 0xFFFF0000u) + a * mb1.z + mb1.w;
        a0 = fmaf(ex, x0 * __builtin_amdgcn_rcpf(1.f + __expf(-x0)), a0);
        a1 = fmaf(ex, x1 * __builtin_amdgcn_rcpf(1.f + __expf(-x1)), a1);
        a2 = fmaf(ex, x2 * __builtin_amdgcn_rcpf(1.f + __expf(-x2)), a2);
        a3 = fmaf(ex, x3 * __builtin_amdgcn_rcpf(1.f + __expf(-x3)), a3);
        ssum += ex;
    }

    if (valid) {
        float inv = __builtin_amdgcn_rcpf(ssum + 1e-16f);
        unsigned pw0 = f2bf(a0 * inv) | (f2bf(a1 * inv) << 16);
        unsigned pw1 = f2bf(a2 * inv) | (f2bf(a3 * inv) << 16);
        *(uint2*)(Sb + (size_t)n * 64 + 2 * l) = make_uint2(pw0, pw1);
        if (l == 0) segsum[n] = ssum;
    }
}

// ---------------------------------------------------------------------------
// node_out (MFMA): out = h + S@Wm2 + bm2 * (segsum/(segsum+1e-16)).
// S already bf16-packed; Wm2 B-frag packed by prep. Tail blocks copy pos.
// ---------------------------------------------------------------------------
__global__ __launch_bounds__(256) void node_out(
    const float* __restrict__ h, int N,
    const unsigned* __restrict__ Sb, const ushort* __restrict__ Wpk2,
    const float* __restrict__ bm2, const float* __restrict__ segsum,
    float* __restrict__ out, const float* __restrict__ pos, int npos, int G1)
{
    int b = blockIdx.x;
    int t = threadIdx.x;
    if (b >= G1) {
        int i = ((b - G1) * 256 + t) * 4;
        float* outp = out + (size_t)N * D;
        if (i + 3 < npos) {
            *(float4*)(outp + i) = *(const float4*)(pos + i);
        } else {
            for (int j = i; j < npos; j++) outp[j] = pos[j];
        }
        return;
    }
    __shared__ __align__(16) ushort ssb[64 * 128];
    int row0 = b * 64;
#pragma unroll
    for (int i = 0; i < 4; i++) {
        int g = t + i * 256;
        int r = g >> 4, c = g & 15;
        int grow = row0 + r;
        uint4 u = make_uint4(0u, 0u, 0u, 0u);
        if (grow < N) u = *(const uint4*)(Sb + (size_t)grow * 64 + c * 4);
        int pc = c ^ (r & 15);
        *(uint4*)&ssb[r * 128 + pc * 8] = u;
    }
    __syncthreads();

    int w = t >> 6, l = t & 63;
    int lrow = w * 16 + (l & 15);
    f32x4 acc[8];
#pragma unroll
    for (int i = 0; i < 8; i++) acc[i] = (f32x4){0.f, 0.f, 0.f, 0.f};

    const bf16x8* WB = (const bf16x8*)Wpk2;
#pragma unroll
    for (int ks = 0; ks < 4; ks++) {
        int c = (ks * 4 + (l >> 4)) ^ (l & 15);
        bf16x8 afrag = *(const bf16x8*)&ssb[lrow * 128 + c * 8];
#pragma unroll
        for (int nt = 0; nt < 8; nt++) {
            bf16x8 bfrag = WB[(nt * 4 + ks) * 64 + l];
            acc[nt] = __builtin_amdgcn_mfma_f32_16x16x32_bf16(afrag, bfrag, acc[nt], 0, 0, 0);
        }
    }

    int rbase = row0 + w * 16 + ((l >> 4) << 2);
    int cl = l & 15;
#pragma unroll
    for (int cc = 0; cc < 8; cc++) {
        float bb = bm2[cc * 16 + cl];
        f32x4 av = acc[cc];
#pragma unroll
        for (int r = 0; r < 4; r++) {
            int row = rbase + r;
            if (row < N) {
                float ws_ = segsum[row];
                ws_ = ws_ / (ws_ + 1e-16f);
                out[(size_t)row * D + cc * 16 + cl] =
                    h[(size_t)row * D + cc * 16 + cl] + av[r] + bb * ws_;
            }
        }
    }
}

extern "C" void kernel_launch(void* const* d_in, const int* in_sizes, int n_in,
                              void* d_out, int out_size, void* d_ws, size_t ws_size,
                              hipStream_t stream)
{
    const float* h     = (const float*)d_in[0];
    const float* pos   = (const float*)d_in[1];
    const int*   ei    = (const int*)d_in[2];
    const float* eattr = (const float*)d_in[3];
    const float* Wq  = (const float*)d_in[4];  const float* bq  = (const float*)d_in[5];
    const float* Wk  = (const float*)d_in[6];  const float* bk  = (const float*)d_in[7];
    const float* Wv  = (const float*)d_in[8];  const float* bv  = (const float*)d_in[9];
    const float* We1 = (const float*)d_in[10]; const float* be1 = (const float*)d_in[11];
    const float* We2 = (const float*)d_in[12]; const float* be2 = (const float*)d_in[13];
    const float* Wa1 = (const float*)d_in[14]; const float* ba1 = (const float*)d_in[15];
    const float* Wa2 = (const float*)d_in[16];
    const float* Wm1 = (const float*)d_in[18]; const float* bm1 = (const float*)d_in[19];
    const float* Wm2 = (const float*)d_in[20]; const float* bm2 = (const float*)d_in[21];

    int N = in_sizes[0] / D;
    int E = in_sizes[3];
    int NB = (N + SB - 1) / SB;

    float* ws = (float*)d_ws;
    size_t off_f = 0;
    auto alloc = [&](size_t n) { float* p = ws + off_f; off_f += (n + 63) & ~(size_t)63; return p; };

    ushort* Wpk  = (ushort*)alloc(24 * 4 * 64 * 8 / 2);
    ushort* Wpk2 = (ushort*)alloc(8 * 4 * 64 * 8 / 2);
    float* bqa = alloc(D); float* bka = alloc(D); float* bva = alloc(D);
    float* bounds = alloc(130);
    float2* AB = (float2*)alloc((size_t)129 * 128 * 2);
    float2* MB = (float2*)alloc((size_t)129 * 128 * 2);
    ushort* qb = (ushort*)alloc((size_t)N * 64);     // bf16 qa
    unsigned* kv = (unsigned*)alloc((size_t)N * D);
    unsigned* Sb = (unsigned*)alloc((size_t)N * 64);
    float* segsum = alloc(N);
    int* deg  = (int*)alloc(N);
    int* offs = (int*)alloc(N);
    int* nodePerm = (int*)alloc(N);
    int* partial = (int*)alloc(256);
    int* blockBin = (int*)alloc(64 * NBMAX);
    int* binStartG = (int*)alloc(64);
    int2* recs = (int2*)alloc((size_t)E * 2);

    hipMemsetAsync(deg, 0, (size_t)N * 4, stream);

    int HB = (E + 255) / 256;
    prep<<<645 + HB, 256, 0, stream>>>(Wq, bq, Wk, bk, Wv, bv, Wa1, ba1, Wm1, bm1,
                                       We1, be1, We2, be2, Wm2, ei, E,
                                       Wpk, Wpk2, bqa, bka, bva, bounds, AB, MB, deg);

    k_scan1<<<NB, SB, 0, stream>>>(deg, N, partial, blockBin);
    if (NB <= BSTRIDE) {
        k_scan23<1><<<NB, SB, 0, stream>>>(deg, N, partial, NB, blockBin, binStartG,
                                           nodePerm, offs);
    } else {
        k_binscan_fallback<<<1, 256, 0, stream>>>(blockBin, NB, binStartG);
        k_scan23<0><<<NB, SB, 0, stream>>>(deg, N, partial, NB, blockBin, binStartG,
                                           nodePerm, offs);
    }

    node_gemm<<<(N + 63) / 64, 256, 0, stream>>>(h, N, Wpk, bqa, bka, bva, qb, kv);

    k_scatter<<<(E + 255) / 256, 256, 0, stream>>>(ei, eattr, E, bounds, offs, recs);

    node_all<<<(N + 7) / 8, 256, 0, stream>>>(recs, N, offs, nodePerm, qb, kv, AB, MB, Wa2,
                                              Sb, segsum);

    int G1 = (N + 63) / 64;
    int G2 = (2 * N + 1023) / 1024;
    node_out<<<G1 + G2, 256, 0, stream>>>(h, N, Sb, Wpk2, bm2, segsum, (float*)d_out,
                                          pos, 2 * N, G1);
}

// Round 15
// 244.611 us; speedup vs baseline: 1.0677x; 1.0677x over previous
//
#include <hip/hip_runtime.h>
#include <math.h>

#define D 128
#define SB 256

typedef __attribute__((ext_vector_type(8))) short bf16x8;
typedef __attribute__((ext_vector_type(4))) float f32x4;

// round-to-nearest-even f32 -> bf16 bits
__device__ inline unsigned f2bf(float f) {
    unsigned u = __float_as_uint(f);
    return (u + 0x7FFFu + ((u >> 16) & 1u)) >> 16;
}

// ---------------------------------------------------------------------------
// prep: one kernel for all precompute + histogram. 256 threads/block,
// heavy sections split-k across two halves (j = t&127, half = t>>7).
//   blocks [0,384)   : folded weights -> bf16 B-fragment-packed Wpk
//   blocks [384,387) : biases bqa/bka/bva (f32)
//   block  387       : global bounds[] (for k_scatter)
//   blocks [388,517) : interval tables AB/MB (recompute bounds locally)
//   blocks [517,645) : Wm2 -> bf16 B-fragment-packed Wpk2
//   blocks 645+      : degree histogram (deg pre-zeroed by memsetAsync)
// ---------------------------------------------------------------------------
__global__ __launch_bounds__(256) void prep(
    const float* __restrict__ Wq, const float* __restrict__ bq,
    const float* __restrict__ Wk, const float* __restrict__ bk,
    const float* __restrict__ Wv, const float* __restrict__ bv,
    const float* __restrict__ Wa1, const float* __restrict__ ba1,
    const float* __restrict__ Wm1, const float* __restrict__ bm1,
    const float* __restrict__ We1, const float* __restrict__ be1,
    const float* __restrict__ We2, const float* __restrict__ be2,
    const float* __restrict__ Wm2,
    const int* __restrict__ ei, int E,
    ushort* __restrict__ Wpk, ushort* __restrict__ Wpk2,
    float* __restrict__ bqa, float* __restrict__ bka, float* __restrict__ bva,
    float* __restrict__ bounds,
    float2* __restrict__ AB, float2* __restrict__ MB,
    int* __restrict__ deg)
{
    __shared__ float smem[1536];
    int b = blockIdx.x;
    int t = threadIdx.x;
    int j = t & 127, half = t >> 7;
    if (b < 384) {
        int which = b >> 7, i = b & 127;   // i = k index
        const float *A, *B;
        if (which == 0)      { A = Wq; B = Wa1; }
        else if (which == 1) { A = Wk; B = Wa1 + 128 * D; }
        else                 { A = Wv; B = Wm1; }
        float acc = 0.f;
        for (int k = half * 64; k < half * 64 + 64; k++) acc += A[i * D + k] * B[k * D + j];
        smem[t] = acc;
        __syncthreads();
        if (half == 0) {
            float v = smem[j] + smem[128 + j];
            int gc = which * 128 + j;
            int nt = gc >> 4;
            int ks = i >> 5;
            int lane = (((i >> 3) & 3) << 4) | (gc & 15);
            int j8 = i & 7;
            Wpk[((nt * 4 + ks) * 64 + lane) * 8 + j8] = (ushort)f2bf(v);
        }
    } else if (b < 387) {
        int which = b - 384;
        const float *bias, *B, *extra; float *out;
        if (which == 0)      { bias = bq; B = Wa1;           out = bqa; extra = ba1; }
        else if (which == 1) { bias = bk; B = Wa1 + 128 * D; out = bka; extra = nullptr; }
        else                 { bias = bv; B = Wm1;           out = bva; extra = bm1; }
        float acc = 0.f;
        for (int k = half * 64; k < half * 64 + 64; k++) acc += bias[k] * B[k * D + j];
        smem[t] = acc;
        __syncthreads();
        if (half == 0) out[j] = smem[j] + smem[128 + j] + (extra ? extra[j] : 0.f);
    } else if (b == 387) {
        float* sb = smem;
        if (t < 128) {
            float w = We1[t], bb = be1[t];
            float th = (w != 0.f) ? (-bb / w) : 2.f;
            sb[t] = fminf(fmaxf(th, 0.f), 1.f);
        }
        __syncthreads();
        for (int k = 2; k <= 128; k <<= 1)
            for (int jj = k >> 1; jj > 0; jj >>= 1) {
                if (t < 128) {
                    int ixj = t ^ jj;
                    if (ixj > t) {
                        float a = sb[t], c = sb[ixj];
                        bool up = ((t & k) == 0);
                        if (up ? (a > c) : (a < c)) { sb[t] = c; sb[ixj] = a; }
                    }
                }
                __syncthreads();
            }
        if (t == 0) { bounds[0] = 0.f; bounds[129] = 1.f; }
        if (t < 128) bounds[1 + t] = sb[t];
    } else if (b < 517) {
        float* sb = smem;            // 128
        float* Ae = smem + 128;      // 128
        float* Be = smem + 256;      // 128
        float* P  = smem + 384;      // 1024
        if (t < 128) {
            float w = We1[t], bb = be1[t];
            float th = (w != 0.f) ? (-bb / w) : 2.f;
            sb[t] = fminf(fmaxf(th, 0.f), 1.f);
        }
        __syncthreads();
        for (int k = 2; k <= 128; k <<= 1)
            for (int jj = k >> 1; jj > 0; jj >>= 1) {
                if (t < 128) {
                    int ixj = t ^ jj;
                    if (ixj > t) {
                        float a = sb[t], c = sb[ixj];
                        bool up = ((t & k) == 0);
                        if (up ? (a > c) : (a < c)) { sb[t] = c; sb[ixj] = a; }
                    }
                }
                __syncthreads();
            }
        int i = b - 388;                  // interval 0..128
        float lo = (i == 0)   ? 0.f : sb[i - 1];
        float hi = (i == 128) ? 1.f : sb[i];
        float m = 0.5f * (lo + hi);
        float ae = 0.f, be = 0.f;
        for (int k = half * 64; k < half * 64 + 64; k++) {
            float ww = We1[k], bb2 = be1[k];
            if (m * ww + bb2 > 0.f) { ae += ww * We2[k * D + j]; be += bb2 * We2[k * D + j]; }
        }
        P[t] = ae; P[256 + t] = be;
        __syncthreads();
        if (half == 0) {
            Ae[j] = P[j] + P[128 + j];
            Be[j] = P[256 + j] + P[384 + j] + be2[j];
        }
        __syncthreads();
        float aa = 0.f, ba = 0.f, am = 0.f, bm = 0.f;
        for (int l2 = half * 64; l2 < half * 64 + 64; l2++) {
            float ael = Ae[l2], bel = Be[l2];
            float wa = Wa1[(256 + l2) * D + j];
            float wm = Wm1[(128 + l2) * D + j];
            aa += ael * wa; ba += bel * wa;
            am += ael * wm; bm += bel * wm;
        }
        P[t] = aa; P[256 + t] = ba; P[512 + t] = am; P[768 + t] = bm;
        __syncthreads();
        if (half == 0) {
            AB[i * 128 + j] = make_float2(P[j] + P[128 + j], P[256 + j] + P[384 + j]);
            MB[i * 128 + j] = make_float2(P[512 + j] + P[640 + j], P[768 + j] + P[896 + j]);
        }
    } else if (b < 645) {
        if (t < 128) {
            int i = b - 517;                  // k row of Wm2
            int nt = t >> 4;
            int ks = i >> 5;
            int lane = (((i >> 3) & 3) << 4) | (t & 15);
            int j8 = i & 7;
            Wpk2[((nt * 4 + ks) * 64 + lane) * 8 + j8] = (ushort)f2bf(Wm2[i * D + t]);
        }
    } else {
        int e = (b - 645) * 256 + t;
        if (e < E) atomicAdd(deg + ei[E + e], 1);
    }
}

// ---------------------------------------------------------------------------
// CSR scan: block sums -> fused scan (redundant partial-scan per block).
// off[] holds EXCLUSIVE starts; k_scatter bumps off[col] so afterwards
// off[n] = inclusive end of segment n.
// ---------------------------------------------------------------------------
__global__ __launch_bounds__(SB) void k_scan1(const int* __restrict__ deg, int N,
                                              int* __restrict__ partial)
{
    __shared__ int ls[SB];
    int t = threadIdx.x;
    int i = blockIdx.x * SB + t;
    ls[t] = (i < N) ? deg[i] : 0;
    __syncthreads();
    for (int s = SB / 2; s > 0; s >>= 1) {
        if (t < s) ls[t] += ls[t + s];
        __syncthreads();
    }
    if (t == 0) partial[blockIdx.x] = ls[0];
}

__global__ __launch_bounds__(SB) void k_scan23(const int* __restrict__ deg, int N,
                                               const int* __restrict__ partial, int NB,
                                               int* __restrict__ off)
{
    __shared__ int lp[SB];
    __shared__ int ls[SB];
    int t = threadIdx.x;
    int pv = (t < NB) ? partial[t] : 0;
    lp[t] = pv;
    __syncthreads();
    int pval = pv;
    for (int s = 1; s < SB; s <<= 1) {
        int add = (t >= s) ? lp[t - s] : 0;
        __syncthreads();
        pval += add;
        lp[t] = pval;
        __syncthreads();
    }
    int base = (blockIdx.x > 0) ? lp[blockIdx.x - 1] : 0;

    int i = blockIdx.x * SB + t;
    int v = (i < N) ? deg[i] : 0;
    ls[t] = v;
    __syncthreads();
    int val = v;
    for (int s = 1; s < SB; s <<= 1) {
        int add = (t >= s) ? ls[t - s] : 0;
        __syncthreads();
        val += add;
        ls[t] = val;
        __syncthreads();
    }
    if (i < N) off[i] = base + val - v;
}

// ---------------------------------------------------------------------------
// k_scatter: standalone (low VGPR, high occupancy). Packs records
// {row | interval<<17, bits(a)} into CSR slots, bumping off[col].
// ---------------------------------------------------------------------------
__global__ __launch_bounds__(256) void k_scatter(const int* __restrict__ ei,
                                                 const float* __restrict__ eattr, int E,
                                                 const float* __restrict__ bounds,
                                                 int* __restrict__ off, int2* __restrict__ recs)
{
    __shared__ float bnd[130];
    int t = threadIdx.x;
    if (t < 130) bnd[t] = bounds[t];
    __syncthreads();
    int e = blockIdx.x * 256 + t;
    if (e >= E) return;
    int row = ei[e], col = ei[E + e];
    float a = eattr[e];
    int lo = 0, hi = 128;
    while (lo < hi) { int mid = (lo + hi + 1) >> 1; if (bnd[mid] <= a) lo = mid; else hi = mid - 1; }
    int p = atomicAdd(off + col, 1);
    recs[p] = make_int2(row | (lo << 17), __float_as_int(a));
}

// ---------------------------------------------------------------------------
// node_gemm (MFMA): [N x 128] @ [128 x 384] in bf16, f32 accum.
// Epilogue writes qa as bf16 (ushort per channel) and packed bf16 kv.
// ---------------------------------------------------------------------------
__global__ __launch_bounds__(256) void node_gemm(
    const float* __restrict__ h, int N,
    const ushort* __restrict__ Wpk,
    const float* __restrict__ bqa, const float* __restrict__ bka, const float* __restrict__ bva,
    ushort* __restrict__ qb, unsigned* __restrict__ kv)
{
    __shared__ __align__(16) ushort hsb[64 * 128];
    int t = threadIdx.x;
    int row0 = blockIdx.x * 64;
#pragma unroll
    for (int i = 0; i < 4; i++) {
        int g = t + i * 256;
        int r = g >> 4, c = g & 15;
        int grow = row0 + r;
        float4 f0, f1;
        if (grow < N) {
            const float4* hp = (const float4*)(h + (size_t)grow * D + c * 8);
            f0 = hp[0]; f1 = hp[1];
        } else {
            f0 = make_float4(0.f, 0.f, 0.f, 0.f); f1 = f0;
        }
        ushort u[8] = { (ushort)f2bf(f0.x), (ushort)f2bf(f0.y), (ushort)f2bf(f0.z), (ushort)f2bf(f0.w),
                        (ushort)f2bf(f1.x), (ushort)f2bf(f1.y), (ushort)f2bf(f1.z), (ushort)f2bf(f1.w) };
        int pc = c ^ (r & 15);
        *(uint4*)&hsb[r * 128 + pc * 8] = *(uint4*)u;
    }
    __syncthreads();

    int w = t >> 6, l = t & 63;
    int lrow = w * 16 + (l & 15);
    f32x4 acc[24];
#pragma unroll
    for (int i = 0; i < 24; i++) acc[i] = (f32x4){0.f, 0.f, 0.f, 0.f};

    const bf16x8* WB = (const bf16x8*)Wpk;
#pragma unroll
    for (int ks = 0; ks < 4; ks++) {
        int c = (ks * 4 + (l >> 4)) ^ (l & 15);
        bf16x8 afrag = *(const bf16x8*)&hsb[lrow * 128 + c * 8];
#pragma unroll
        for (int nt = 0; nt < 24; nt++) {
            bf16x8 bfrag = WB[(nt * 4 + ks) * 64 + l];
            acc[nt] = __builtin_amdgcn_mfma_f32_16x16x32_bf16(afrag, bfrag, acc[nt], 0, 0, 0);
        }
    }

    int rbase = row0 + w * 16 + ((l >> 4) << 2);
    int cl = l & 15;
#pragma unroll
    for (int cc = 0; cc < 8; cc++) {
        float bqv = bqa[cc * 16 + cl];
        float bkv = bka[cc * 16 + cl];
        float bvv = bva[cc * 16 + cl];
        f32x4 aq = acc[cc], ak = acc[8 + cc], av = acc[16 + cc];
#pragma unroll
        for (int r = 0; r < 4; r++) {
            int row = rbase + r;
            if (row < N) {
                qb[(size_t)row * D + cc * 16 + cl] = (ushort)f2bf(aq[r] + bqv);
                kv[(size_t)row * D + cc * 16 + cl] =
                    (f2bf(av[r] + bvv) << 16) | f2bf(ak[r] + bkv);
            }
        }
    }
}

// ---------------------------------------------------------------------------
// node_all (R8 structure): 32 lanes per destination node (2 nodes/wave).
// Defer-max online softmax (rescale only when max grows by >8; ba2 dropped).
// 2-edge unroll batches 12 loads per pair. bf16 q input. Emits bf16 S + segsum.
// ---------------------------------------------------------------------------
__global__ __launch_bounds__(256) void node_all(
    const int2* __restrict__ recs, int N,
    const int* __restrict__ off,
    const ushort* __restrict__ qb, const unsigned* __restrict__ kv,
    const float2* __restrict__ AB, const float2* __restrict__ MB,
    const float* __restrict__ Wa2,
    unsigned* __restrict__ Sb, float* __restrict__ segsum)
{
    int t = threadIdx.x;
    int l = t & 31;
    int n = blockIdx.x * 8 + (t >> 5);
    bool valid = (n < N);
    int start = 0, end = 0;
    if (valid) {
        end = off[n];
        start = (n > 0) ? off[n - 1] : 0;
    }

    const char* kvc = (const char*)kv;
    const char* ABc = (const char*)AB;
    const char* MBc = (const char*)MB;

    uint2 qp = valid ? *(const uint2*)(qb + (size_t)n * D + 4 * l) : make_uint2(0u, 0u);
    float q0 = __uint_as_float(qp.x << 16);
    float q1 = __uint_as_float(qp.x & 0xFFFF0000u);
    float q2 = __uint_as_float(qp.y << 16);
    float q3 = __uint_as_float(qp.y & 0xFFFF0000u);
    float4 w4 = *(const float4*)(Wa2 + 4 * l);

    float m_run = -INFINITY;
    float a0 = 0.f, a1 = 0.f, a2 = 0.f, a3 = 0.f, ssum = 0.f;

    int idx = start;
    for (; idx + 2 <= end; idx += 2) {
        int2 rec1 = recs[idx];
        int2 rec2 = recs[idx + 1];
        unsigned u1 = (unsigned)rec1.x, u2 = (unsigned)rec2.x;
        float at1 = __int_as_float(rec1.y), at2 = __int_as_float(rec2.y);
        int rb1 = (int)(u1 & 0x1FFFFu) << 9, tb1 = (int)(u1 >> 17) << 10;
        int rb2 = (int)(u2 & 0x1FFFFu) << 9, tb2 = (int)(u2 >> 17) << 10;

        uint4 kp1 = *(const uint4*)(kvc + rb1 + (l << 4));
        uint4 kp2 = *(const uint4*)(kvc + rb2 + (l << 4));
        float4 ab0a = *(const float4*)(ABc + tb1 + (l << 5));
        float4 ab1a = *(const float4*)(ABc + tb1 + (l << 5) + 16);
        float4 mb0a = *(const float4*)(MBc + tb1 + (l << 5));
        float4 mb1a = *(const float4*)(MBc + tb1 + (l << 5) + 16);
        float4 ab0b = *(const float4*)(ABc + tb2 + (l << 5));
        float4 ab1b = *(const float4*)(ABc + tb2 + (l << 5) + 16);
        float4 mb0b = *(const float4*)(MBc + tb2 + (l << 5));
        float4 mb1b = *(const float4*)(MBc + tb2 + (l << 5) + 16);

        float p1 = fmaxf(q0 + __uint_as_float(kp1.x << 16) + at1 * ab0a.x + ab0a.y, 0.f) * w4.x
                 + fmaxf(q1 + __uint_as_float(kp1.y << 16) + at1 * ab0a.z + ab0a.w, 0.f) * w4.y
                 + fmaxf(q2 + __uint_as_float(kp1.z << 16) + at1 * ab1a.x + ab1a.y, 0.f) * w4.z
                 + fmaxf(q3 + __uint_as_float(kp1.w << 16) + at1 * ab1a.z + ab1a.w, 0.f) * w4.w;
        float p2 = fmaxf(q0 + __uint_as_float(kp2.x << 16) + at2 * ab0b.x + ab0b.y, 0.f) * w4.x
                 + fmaxf(q1 + __uint_as_float(kp2.y << 16) + at2 * ab0b.z + ab0b.w, 0.f) * w4.y
                 + fmaxf(q2 + __uint_as_float(kp2.z << 16) + at2 * ab1b.x + ab1b.y, 0.f) * w4.z
                 + fmaxf(q3 + __uint_as_float(kp2.w << 16) + at2 * ab1b.z + ab1b.w, 0.f) * w4.w;
#pragma unroll
        for (int s = 1; s < 32; s <<= 1) {
            p1 += __shfl_xor(p1, s, 64);
            p2 += __shfl_xor(p2, s, 64);
        }
        float d1 = p1 - m_run, d2 = p2 - m_run;
        if (fmaxf(d1, d2) > 8.f) {           // rare: max grew a lot (or first pair)
            float mN = fmaxf(fmaxf(p1, p2), m_run);
            float sc = __expf(m_run - mN);   // 0 on first pair
            a0 *= sc; a1 *= sc; a2 *= sc; a3 *= sc; ssum *= sc;
            m_run = mN; d1 = p1 - mN; d2 = p2 - mN;
        }
        float ex1 = __expf(d1), ex2 = __expf(d2);

        float x0 = __uint_as_float(kp1.x & 0xFFFF0000u) + at1 * mb0a.x + mb0a.y;
        float x1 = __uint_as_float(kp1.y & 0xFFFF0000u) + at1 * mb0a.z + mb0a.w;
        float x2 = __uint_as_float(kp1.z & 0xFFFF0000u) + at1 * mb1a.x + mb1a.y;
        float x3 = __uint_as_float(kp1.w & 0xFFFF0000u) + at1 * mb1a.z + mb1a.w;
        float y0 = __uint_as_float(kp2.x & 0xFFFF0000u) + at2 * mb0b.x + mb0b.y;
        float y1 = __uint_as_float(kp2.y & 0xFFFF0000u) + at2 * mb0b.z + mb0b.w;
        float y2 = __uint_as_float(kp2.z & 0xFFFF0000u) + at2 * mb1b.x + mb1b.y;
        float y3 = __uint_as_float(kp2.w & 0xFFFF0000u) + at2 * mb1b.z + mb1b.w;
        float s10 = x0 * __builtin_amdgcn_rcpf(1.f + __expf(-x0));
        float s11 = x1 * __builtin_amdgcn_rcpf(1.f + __expf(-x1));
        float s12 = x2 * __builtin_amdgcn_rcpf(1.f + __expf(-x2));
        float s13 = x3 * __builtin_amdgcn_rcpf(1.f + __expf(-x3));
        float s20 = y0 * __builtin_amdgcn_rcpf(1.f + __expf(-y0));
        float s21 = y1 * __builtin_amdgcn_rcpf(1.f + __expf(-y1));
        float s22 = y2 * __builtin_amdgcn_rcpf(1.f + __expf(-y2));
        float s23 = y3 * __builtin_amdgcn_rcpf(1.f + __expf(-y3));

        a0 = fmaf(ex2, s20, fmaf(ex1, s10, a0));
        a1 = fmaf(ex2, s21, fmaf(ex1, s11, a1));
        a2 = fmaf(ex2, s22, fmaf(ex1, s12, a2));
        a3 = fmaf(ex2, s23, fmaf(ex1, s13, a3));
        ssum += ex1 + ex2;
    }
    if (idx < end) {   // odd tail
        int2 rec = recs[idx];
        unsigned u1 = (unsigned)rec.x;
        float a = __int_as_float(rec.y);
        int rb = (int)(u1 & 0x1FFFFu) << 9, tb = (int)(u1 >> 17) << 10;
        uint4 kp = *(const uint4*)(kvc + rb + (l << 4));
        float4 ab0 = *(const float4*)(ABc + tb + (l << 5));
        float4 ab1 = *(const float4*)(ABc + tb + (l << 5) + 16);
        float4 mb0 = *(const float4*)(MBc + tb + (l << 5));
        float4 mb1 = *(const float4*)(MBc + tb + (l << 5) + 16);
        float p1 = fmaxf(q0 + __uint_as_float(kp.x << 16) + a * ab0.x + ab0.y, 0.f) * w4.x
                 + fmaxf(q1 + __uint_as_float(kp.y << 16) + a * ab0.z + ab0.w, 0.f) * w4.y
                 + fmaxf(q2 + __uint_as_float(kp.z << 16) + a * ab1.x + ab1.y, 0.f) * w4.z
                 + fmaxf(q3 + __uint_as_float(kp.w << 16) + a * ab1.z + ab1.w, 0.f) * w4.w;
#pragma unroll
        for (int s = 1; s < 32; s <<= 1) p1 += __shfl_xor(p1, s, 64);
        float d1 = p1 - m_run;
        if (d1 > 8.f) {
            float mN = p1;
            float sc = __expf(m_run - mN);
            a0 *= sc; a1 *= sc; a2 *= sc; a3 *= sc; ssum *= sc;
            m_run = mN; d1 = 0.f;
        }
        float ex = __expf(d1);
        float x0 = __uint_as_float(kp.x & 0xFFFF0000u) + a * mb0.x + mb0.y;
        float x1 = __uint_as_float(kp.y & 0xFFFF0000u) + a * mb0.z + mb0.w;
        float x2 = __uint_as_float(kp.z & 0xFFFF0000u) + a * mb1.x + mb1.y;
        float x3 = __uint_as_float(kp.w & 0xFFFF0000u) + a * mb1.z + mb1.w;
        a0 = fmaf(ex, x0 * __builtin_amdgcn_rcpf(1.f + __expf(-x0)), a0);
        a1 = fmaf(ex, x1 * __builtin_amdgcn_rcpf(1.f + __expf(-x1)), a1);
        a2 = fmaf(ex, x2 * __builtin_amdgcn_rcpf(1.f + __expf(-x2)), a2);
        a3 = fmaf(ex, x3 * __builtin_amdgcn_rcpf(1.f + __expf(-x3)), a3);
        ssum += ex;
    }

    if (valid) {
        float inv = __builtin_amdgcn_rcpf(ssum + 1e-16f);
        unsigned pw0 = f2bf(a0 * inv) | (f2bf(a1 * inv) << 16);
        unsigned pw1 = f2bf(a2 * inv) | (f2bf(a3 * inv) << 16);
        *(uint2*)(Sb + (size_t)n * 64 + 2 * l) = make_uint2(pw0, pw1);
        if (l == 0) segsum[n] = ssum;
    }
}

// ---------------------------------------------------------------------------
// node_out (MFMA): out = h + S@Wm2 + bm2 * (segsum/(segsum+1e-16)).
// S already bf16-packed; Wm2 B-frag packed by prep. Tail blocks copy pos.
// ---------------------------------------------------------------------------
__global__ __launch_bounds__(256) void node_out(
    const float* __restrict__ h, int N,
    const unsigned* __restrict__ Sb, const ushort* __restrict__ Wpk2,
    const float* __restrict__ bm2, const float* __restrict__ segsum,
    float* __restrict__ out, const float* __restrict__ pos, int npos, int G1)
{
    int b = blockIdx.x;
    int t = threadIdx.x;
    if (b >= G1) {
        int i = ((b - G1) * 256 + t) * 4;
        float* outp = out + (size_t)N * D;
        if (i + 3 < npos) {
            *(float4*)(outp + i) = *(const float4*)(pos + i);
        } else {
            for (int j = i; j < npos; j++) outp[j] = pos[j];
        }
        return;
    }
    __shared__ __align__(16) ushort ssb[64 * 128];
    int row0 = b * 64;
#pragma unroll
    for (int i = 0; i < 4; i++) {
        int g = t + i * 256;
        int r = g >> 4, c = g & 15;
        int grow = row0 + r;
        uint4 u = make_uint4(0u, 0u, 0u, 0u);
        if (grow < N) u = *(const uint4*)(Sb + (size_t)grow * 64 + c * 4);
        int pc = c ^ (r & 15);
        *(uint4*)&ssb[r * 128 + pc * 8] = u;
    }
    __syncthreads();

    int w = t >> 6, l = t & 63;
    int lrow = w * 16 + (l & 15);
    f32x4 acc[8];
#pragma unroll
    for (int i = 0; i < 8; i++) acc[i] = (f32x4){0.f, 0.f, 0.f, 0.f};

    const bf16x8* WB = (const bf16x8*)Wpk2;
#pragma unroll
    for (int ks = 0; ks < 4; ks++) {
        int c = (ks * 4 + (l >> 4)) ^ (l & 15);
        bf16x8 afrag = *(const bf16x8*)&ssb[lrow * 128 + c * 8];
#pragma unroll
        for (int nt = 0; nt < 8; nt++) {
            bf16x8 bfrag = WB[(nt * 4 + ks) * 64 + l];
            acc[nt] = __builtin_amdgcn_mfma_f32_16x16x32_bf16(afrag, bfrag, acc[nt], 0, 0, 0);
        }
    }

    int rbase = row0 + w * 16 + ((l >> 4) << 2);
    int cl = l & 15;
#pragma unroll
    for (int cc = 0; cc < 8; cc++) {
        float bb = bm2[cc * 16 + cl];
        f32x4 av = acc[cc];
#pragma unroll
        for (int r = 0; r < 4; r++) {
            int row = rbase + r;
            if (row < N) {
                float ws_ = segsum[row];
                ws_ = ws_ / (ws_ + 1e-16f);
                out[(size_t)row * D + cc * 16 + cl] =
                    h[(size_t)row * D + cc * 16 + cl] + av[r] + bb * ws_;
            }
        }
    }
}

extern "C" void kernel_launch(void* const* d_in, const int* in_sizes, int n_in,
                              void* d_out, int out_size, void* d_ws, size_t ws_size,
                              hipStream_t stream)
{
    const float* h     = (const float*)d_in[0];
    const float* pos   = (const float*)d_in[1];
    const int*   ei    = (const int*)d_in[2];
    const float* eattr = (const float*)d_in[3];
    const float* Wq  = (const float*)d_in[4];  const float* bq  = (const float*)d_in[5];
    const float* Wk  = (const float*)d_in[6];  const float* bk  = (const float*)d_in[7];
    const float* Wv  = (const float*)d_in[8];  const float* bv  = (const float*)d_in[9];
    const float* We1 = (const float*)d_in[10]; const float* be1 = (const float*)d_in[11];
    const float* We2 = (const float*)d_in[12]; const float* be2 = (const float*)d_in[13];
    const float* Wa1 = (const float*)d_in[14]; const float* ba1 = (const float*)d_in[15];
    const float* Wa2 = (const float*)d_in[16];
    const float* Wm1 = (const float*)d_in[18]; const float* bm1 = (const float*)d_in[19];
    const float* Wm2 = (const float*)d_in[20]; const float* bm2 = (const float*)d_in[21];

    int N = in_sizes[0] / D;
    int E = in_sizes[3];
    int NB = (N + SB - 1) / SB;

    float* ws = (float*)d_ws;
    size_t off_f = 0;
    auto alloc = [&](size_t n) { float* p = ws + off_f; off_f += (n + 63) & ~(size_t)63; return p; };

    ushort* Wpk  = (ushort*)alloc(24 * 4 * 64 * 8 / 2);
    ushort* Wpk2 = (ushort*)alloc(8 * 4 * 64 * 8 / 2);
    float* bqa = alloc(D); float* bka = alloc(D); float* bva = alloc(D);
    float* bounds = alloc(130);
    float2* AB = (float2*)alloc((size_t)129 * 128 * 2);
    float2* MB = (float2*)alloc((size_t)129 * 128 * 2);
    ushort* qb = (ushort*)alloc((size_t)N * 64);     // bf16 qa
    unsigned* kv = (unsigned*)alloc((size_t)N * D);
    unsigned* Sb = (unsigned*)alloc((size_t)N * 64);
    float* segsum = alloc(N);
    int* deg  = (int*)alloc(N);
    int* offs = (int*)alloc(N);
    int* partial = (int*)alloc(256);
    int2* recs = (int2*)alloc((size_t)E * 2);

    hipMemsetAsync(deg, 0, (size_t)N * 4, stream);

    int HB = (E + 255) / 256;
    prep<<<645 + HB, 256, 0, stream>>>(Wq, bq, Wk, bk, Wv, bv, Wa1, ba1, Wm1, bm1,
                                       We1, be1, We2, be2, Wm2, ei, E,
                                       Wpk, Wpk2, bqa, bka, bva, bounds, AB, MB, deg);

    k_scan1<<<NB, SB, 0, stream>>>(deg, N, partial);
    k_scan23<<<NB, SB, 0, stream>>>(deg, N, partial, NB, offs);

    node_gemm<<<(N + 63) / 64, 256, 0, stream>>>(h, N, Wpk, bqa, bka, bva, qb, kv);

    k_scatter<<<(E + 255) / 256, 256, 0, stream>>>(ei, eattr, E, bounds, offs, recs);

    node_all<<<(N + 7) / 8, 256, 0, stream>>>(recs, N, offs, qb, kv, AB, MB, Wa2,
                                              Sb, segsum);

    int G1 = (N + 63) / 64;
    int G2 = (2 * N + 1023) / 1024;
    node_out<<<G1 + G2, 256, 0, stream>>>(h, N, Sb, Wpk2, bm2, segsum, (float*)d_out,
                                          pos, 2 * N, G1);
}